// Round 3
// baseline (109.998 us; speedup 1.0000x reference)
//
#include <hip/hip_runtime.h>
#include <math.h>

// GAT forward, B=8, N=2048, F=64.
// e[b,i,j] = leakyrelu(c_i + d_j) is rank-structured; leakyrelu is piecewise
// linear with one breakpoint, so softmax(e)@Wh reduces per row to TWO
// threshold-set sums over j (d_j > -c_i vs <=). With d sorted per batch these
// are suffix/prefix scans: O(B*N*F) total instead of O(B*N^2*F).
// Round 3: both transpose sides coalesced. K3a permutes Wh into sorted order
// (Y1/Y2, coalesced writes) + chunk totals; K3b writes Suf/Pre in [k][o]
// layout (coalesced); K4 reads [k][o] rows coalesced (was the ~40us scatter).

#define B 8
#define N 2048
#define F 64
#define NROW (B * N)      // 16384
#define NK (N + 1)        // scan boundaries 0..N
#define STP 80            // padded channel stride for Suf/Pre rows (64B-aligned)
#define CHK 64            // ranks per chunk
#define NCH (N / CHK)     // 32 chunks per batch

__device__ __forceinline__ unsigned int ord32(float v) {
  unsigned int u = __float_as_uint(v);
  return (u & 0x80000000u) ? ~u : (u | 0x80000000u);
}

// ---- K1: Wh = h@W ; c = Wh@a_src ; d = Wh@a_dst ----------------------------
__global__ __launch_bounds__(256) void k_wh(const float* __restrict__ h,
                                            const float* __restrict__ W,
                                            const float* __restrict__ a,
                                            float* __restrict__ Wh,
                                            float* __restrict__ c,
                                            float* __restrict__ d) {
  __shared__ float hl[1024];                 // 16 rows x 64
  int t = threadIdx.x, lane = t & 63, wid = t >> 6;
  int blk = blockIdx.x;
  *(float4*)&hl[t * 4] = *(const float4*)&h[(size_t)blk * 1024 + t * 4];
  float wreg[64];
#pragma unroll
  for (int k = 0; k < 64; ++k) wreg[k] = W[k * 64 + lane];
  float as = a[lane], ad = a[64 + lane];
  __syncthreads();
#pragma unroll
  for (int rr = 0; rr < 4; ++rr) {
    int rl = wid * 4 + rr;
    int row = blk * 16 + rl;
    float acc = 0.f;
#pragma unroll
    for (int kk = 0; kk < 16; ++kk) {
      float4 hq = *(const float4*)&hl[rl * 64 + kk * 4];
      acc = fmaf(hq.x, wreg[kk * 4 + 0], acc);
      acc = fmaf(hq.y, wreg[kk * 4 + 1], acc);
      acc = fmaf(hq.z, wreg[kk * 4 + 2], acc);
      acc = fmaf(hq.w, wreg[kk * 4 + 3], acc);
    }
    Wh[(size_t)row * 64 + lane] = acc;
    float ps = acc * as, pd = acc * ad;
#pragma unroll
    for (int off = 32; off > 0; off >>= 1) {
      ps += __shfl_xor(ps, off, 64);
      pd += __shfl_xor(pd, off, 64);
    }
    if (lane == 0) { c[row] = ps; d[row] = pd; }
  }
}

// ---- K2: fused rank-sort + batch-max + threshold-count ---------------------
__global__ __launch_bounds__(256) void k_rank(const float* __restrict__ d,
                                              const float* __restrict__ c,
                                              float* __restrict__ E1,
                                              float* __restrict__ E2,
                                              int* __restrict__ perm,
                                              int* __restrict__ kidx,
                                              float* __restrict__ M) {
  int t = threadIdx.x, lane = t & 63, wid = t >> 6;
  int row = blockIdx.x * 4 + wid;
  int b = row >> 11, j = row & (N - 1);
  const float* db = d + b * N;
  float dj = db[j];                          // wave-uniform
  float thr = -c[row];
  unsigned long long kj = ((unsigned long long)ord32(dj) << 11) | (unsigned)j;
  int cnt = 0, cnt2 = 0;
  float m = -INFINITY;
#pragma unroll 8
  for (int it = 0; it < N / 64; ++it) {
    int jj = it * 64 + lane;
    float v = db[jj];
    unsigned long long kv = ((unsigned long long)ord32(v) << 11) | (unsigned)jj;
    cnt  += (kv < kj) ? 1 : 0;
    cnt2 += (v <= thr) ? 1 : 0;
    m = fmaxf(m, v);
  }
#pragma unroll
  for (int off = 32; off > 0; off >>= 1) {
    cnt  += __shfl_xor(cnt,  off, 64);
    cnt2 += __shfl_xor(cnt2, off, 64);
    m = fmaxf(m, __shfl_xor(m, off, 64));
  }
  if (lane == 0) {
    int r = b * N + cnt;
    E1[r]   = __expf(dj - m);                // <= 1
    E2[r]   = __expf(0.2f * (dj - m));       // <= 1
    perm[r] = j;
    kidx[row] = cnt2;
    if (j == 0) M[b] = m;
  }
}

// ---- K3a: permute Wh into sorted order, fold E, chunk totals ---------------
// Block = (chunk, b). Thread (rl,q): rank rl (0..63 in chunk), 16 channels
// [q*16,q*16+16). Writes Y1/Y2 coalesced; chunk totals via shfl (determ.).
__global__ __launch_bounds__(256) void k_permE(const float* __restrict__ Wh,
                                               const int* __restrict__ perm,
                                               const float* __restrict__ E1,
                                               const float* __restrict__ E2,
                                               float* __restrict__ Y1,
                                               float* __restrict__ Y2,
                                               float* __restrict__ T1,
                                               float* __restrict__ T2,
                                               float* __restrict__ Td1,
                                               float* __restrict__ Td2) {
  __shared__ float part1[4][64], part2[4][64];
  int chunk = blockIdx.x, b = blockIdx.y;
  int t = threadIdx.x, lane = t & 63, w = t >> 6;
  int rl = t >> 2, q = t & 3;                // rank-local 0..63, quarter 0..3
  int gr = b * N + chunk * CHK + rl;         // sorted-rank global index
  int p = perm[gr];
  float e1 = E1[gr], e2 = E2[gr];
  const float4* src = (const float4*)(Wh + ((size_t)b * N + p) * 64 + q * 16);
  float4* y1p = (float4*)(Y1 + (size_t)gr * 64 + q * 16);
  float4* y2p = (float4*)(Y2 + (size_t)gr * 64 + q * 16);
  float a1[16], a2[16];
#pragma unroll
  for (int i = 0; i < 4; ++i) {
    float4 v = src[i];
    float4 w1 = { v.x * e1, v.y * e1, v.z * e1, v.w * e1 };
    float4 w2 = { v.x * e2, v.y * e2, v.z * e2, v.w * e2 };
    y1p[i] = w1; y2p[i] = w2;
    a1[i * 4 + 0] = w1.x; a1[i * 4 + 1] = w1.y; a1[i * 4 + 2] = w1.z; a1[i * 4 + 3] = w1.w;
    a2[i * 4 + 0] = w2.x; a2[i * 4 + 1] = w2.y; a2[i * 4 + 2] = w2.z; a2[i * 4 + 3] = w2.w;
  }
  // reduce over the 16 ranks this wave holds (lane bits 2..5), per channel
#pragma unroll
  for (int cix = 0; cix < 16; ++cix) {
    float v1 = a1[cix], v2 = a2[cix];
#pragma unroll
    for (int off = 4; off < 64; off <<= 1) {
      v1 += __shfl_xor(v1, off, 64);
      v2 += __shfl_xor(v2, off, 64);
    }
    a1[cix] = v1; a2[cix] = v2;
  }
  if (lane < 4) {                            // q == lane here
#pragma unroll
    for (int cix = 0; cix < 16; ++cix) {
      part1[w][lane * 16 + cix] = a1[cix];
      part2[w][lane * 16 + cix] = a2[cix];
    }
  }
  __syncthreads();
  if (t < 64) {
    float s1 = part1[0][t] + part1[1][t] + part1[2][t] + part1[3][t];
    float s2 = part2[0][t] + part2[1][t] + part2[2][t] + part2[3][t];
    T1[((size_t)b * NCH + chunk) * 64 + t] = s1;
    T2[((size_t)b * NCH + chunk) * 64 + t] = s2;
  }
  if (t >= 64 && t < 128) {                  // wave 1: denominator totals
    int lr = t - 64;
    float v1 = E1[b * N + chunk * CHK + lr];
    float v2 = E2[b * N + chunk * CHK + lr];
#pragma unroll
    for (int off = 1; off < 64; off <<= 1) {
      v1 += __shfl_xor(v1, off, 64);
      v2 += __shfl_xor(v2, off, 64);
    }
    if (lr == 0) { Td1[b * NCH + chunk] = v1; Td2[b * NCH + chunk] = v2; }
  }
}

// ---- K3b: within-chunk scans + cross-chunk bases -> Suf/Pre [k][o] ---------
__global__ __launch_bounds__(256) void k_scan2(const float* __restrict__ Y1,
                                               const float* __restrict__ Y2,
                                               const float* __restrict__ E1,
                                               const float* __restrict__ E2,
                                               const float* __restrict__ T1,
                                               const float* __restrict__ T2,
                                               const float* __restrict__ Td1,
                                               const float* __restrict__ Td2,
                                               float* __restrict__ Suf,
                                               float* __restrict__ Pre) {
  __shared__ float wt1[4][64], wt2[4][64];
  int chunk = blockIdx.x, b = blockIdx.y;
  int t = threadIdx.x, o = t & 63, w = t >> 6;
  int cb = chunk * CHK;
  size_t ybase = ((size_t)b * N + cb + w * 16) * 64 + o;
  float pex[16]; float run2 = 0.f;           // exclusive prefix of Y2
#pragma unroll
  for (int i = 0; i < 16; ++i) { pex[i] = run2; run2 += Y2[ybase + (size_t)i * 64]; }
  float sin_[16]; float run1 = 0.f;          // inclusive suffix of Y1
#pragma unroll
  for (int i = 15; i >= 0; --i) { run1 += Y1[ybase + (size_t)i * 64]; sin_[i] = run1; }
  wt2[w][o] = run2; wt1[w][o] = run1;
  __syncthreads();
  float bw2 = 0.f, aw1 = 0.f, allw2 = 0.f;
#pragma unroll
  for (int w2 = 0; w2 < 4; ++w2) {
    float v2 = wt2[w2][o];
    allw2 += v2;
    if (w2 < w) bw2 += v2;
    if (w2 > w) aw1 += wt1[w2][o];
  }
  float bc2 = 0.f, ac1 = 0.f;
  for (int cc = 0; cc < NCH; ++cc) {
    float t2v = T2[((size_t)b * NCH + cc) * 64 + o];
    float t1v = T1[((size_t)b * NCH + cc) * 64 + o];
    if (cc < chunk) bc2 += t2v;
    if (cc > chunk) ac1 += t1v;
  }
  float base2 = bc2 + bw2, after1 = ac1 + aw1;
  size_t obase = ((size_t)b * NK + cb + w * 16) * STP + o;
#pragma unroll
  for (int i = 0; i < 16; ++i) {
    Pre[obase + (size_t)i * STP] = base2 + pex[i];
    Suf[obase + (size_t)i * STP] = after1 + sin_[i];
  }
  if (chunk == NCH - 1 && w == 3) {          // k = N boundary
    Pre[((size_t)b * NK + N) * STP + o] = bc2 + allw2;
    Suf[((size_t)b * NK + N) * STP + o] = 0.f;
  }
  if (w == 0) {                              // denominator channel (o == 64)
    int lr = o;
    int gr = b * N + cb + lr;
    float e1 = E1[gr], e2 = E2[gr];
    float ip2 = e2;                          // inclusive prefix across 64 lanes
#pragma unroll
    for (int off = 1; off < 64; off <<= 1) {
      float v = __shfl_up(ip2, off, 64);
      if (lr >= off) ip2 += v;
    }
    float is1 = e1;                          // inclusive suffix
#pragma unroll
    for (int off = 1; off < 64; off <<= 1) {
      float v = __shfl_down(is1, off, 64);
      if (lr < 64 - off) is1 += v;
    }
    float db2 = 0.f, da1 = 0.f;
    for (int cc = 0; cc < NCH; ++cc) {
      float v2 = Td2[b * NCH + cc], v1 = Td1[b * NCH + cc];
      if (cc < chunk) db2 += v2;
      if (cc > chunk) da1 += v1;
    }
    size_t kb = ((size_t)b * NK + cb + lr) * STP + 64;
    Pre[kb] = db2 + (ip2 - e2);
    Suf[kb] = da1 + is1;
    if (chunk == NCH - 1 && lr == 63) {
      Pre[((size_t)b * NK + N) * STP + 64] = db2 + ip2;
      Suf[((size_t)b * NK + N) * STP + 64] = 0.f;
    }
  }
}

// ---- K4: combine + ELU (coalesced [k][o] reads) ----------------------------
__global__ __launch_bounds__(256) void k_final(const float* __restrict__ c,
                                               const float* __restrict__ M,
                                               const int* __restrict__ kidx,
                                               const float* __restrict__ Suf,
                                               const float* __restrict__ Pre,
                                               float* __restrict__ out) {
  int t = threadIdx.x, lane = t & 63, wid = t >> 6;
  int row = blockIdx.x * 4 + wid;
  int b = row >> 11;
  int k = kidx[row];
  float cpM = c[row] + M[b];
  float f1, f2;                              // exponents <= 0: no overflow
  if (cpM > 0.f) { f1 = 1.f;                 f2 = __expf(-0.8f * cpM); }
  else           { f1 = __expf(0.8f * cpM);  f2 = 1.f; }
  size_t base = ((size_t)b * NK + k) * STP;
  float S  = Suf[base + lane], P  = Pre[base + lane];
  float Sd = Suf[base + 64],   Pd = Pre[base + 64];
  float v = (f1 * S + f2 * P) / (f1 * Sd + f2 * Pd);
  out[(size_t)row * 64 + lane] = (v > 0.f) ? v : expm1f(v);   // ELU alpha=1
}

// ---- launch -----------------------------------------------------------------
extern "C" void kernel_launch(void* const* d_in, const int* in_sizes, int n_in,
                              void* d_out, int out_size, void* d_ws, size_t ws_size,
                              hipStream_t stream) {
  (void)in_sizes; (void)n_in; (void)out_size; (void)ws_size;
  const float* h = (const float*)d_in[0];
  const float* W = (const float*)d_in[1];
  const float* a = (const float*)d_in[2];
  float* out = (float*)d_out;

  float* ws = (float*)d_ws;
  size_t off = 0;
  float* Wh   = ws + off; off += (size_t)NROW * F;          // 4 MB
  float* c    = ws + off; off += NROW;
  float* d    = ws + off; off += NROW;
  float* E1   = ws + off; off += NROW;
  float* E2   = ws + off; off += NROW;
  float* M    = ws + off; off += 16;
  int*   perm = (int*)(ws + off); off += NROW;
  int*   kidx = (int*)(ws + off); off += NROW;
  float* Y1   = ws + off; off += (size_t)NROW * F;          // 4 MB
  float* Y2   = ws + off; off += (size_t)NROW * F;          // 4 MB
  float* T1   = ws + off; off += (size_t)B * NCH * 64;      // 64 KB
  float* T2   = ws + off; off += (size_t)B * NCH * 64;
  float* Td1  = ws + off; off += (size_t)B * NCH;
  float* Td2  = ws + off; off += (size_t)B * NCH;
  float* Suf  = ws + off; off += (size_t)B * NK * STP;      // 5.25 MB
  float* Pre  = ws + off; off += (size_t)B * NK * STP;      // 5.25 MB

  k_wh   <<<NROW / 16, 256, 0, stream>>>(h, W, a, Wh, c, d);
  k_rank <<<NROW / 4,  256, 0, stream>>>(d, c, E1, E2, perm, kidx, M);
  k_permE<<<dim3(NCH, B), 256, 0, stream>>>(Wh, perm, E1, E2, Y1, Y2, T1, T2, Td1, Td2);
  k_scan2<<<dim3(NCH, B), 256, 0, stream>>>(Y1, Y2, E1, E2, T1, T2, Td1, Td2, Suf, Pre);
  k_final<<<NROW / 4,  256, 0, stream>>>(c, M, kidx, Suf, Pre, out);
}

// Round 5
// 106.184 us; speedup vs baseline: 1.0359x; 1.0359x over previous
//
#include <hip/hip_runtime.h>
#include <math.h>

// GAT forward, B=8, N=2048, F=64.
// e[b,i,j] = leakyrelu(c_i + d_j) is rank-structured; leakyrelu is piecewise
// linear with one breakpoint, so softmax(e)@Wh reduces per row to TWO
// threshold-set sums over j (d_j > -c_i vs <=). With d sorted per batch these
// are suffix/prefix scans: O(B*N*F) total instead of O(B*N^2*F).
//   m_i = g(c_i + max_j d_j)  (g monotone) -> analytic row max, exponents <= 0.
// R4/R5: lean 4-kernel pipeline (R2 structure); k_rank does 2 rows/wave with
// packed count reductions (~40% less VALU, half the L2 reads).

#define B 8
#define N 2048
#define F 64
#define NROW (B * N)      // 16384
#define NKP 2052          // 2049 scan boundaries padded to /4 for float4
#define ST 65             // 64 features + 1 denominator channel

__device__ __forceinline__ unsigned int ord32(float v) {
  unsigned int u = __float_as_uint(v);
  return (u & 0x80000000u) ? ~u : (u | 0x80000000u);
}

// ---- K1: Wh = h@W ; c = Wh@a_src ; d = Wh@a_dst ----------------------------
__global__ __launch_bounds__(256) void k_wh(const float* __restrict__ h,
                                            const float* __restrict__ W,
                                            const float* __restrict__ a,
                                            float* __restrict__ Wh,
                                            float* __restrict__ c,
                                            float* __restrict__ d) {
  __shared__ float hl[1024];                 // 16 rows x 64
  int t = threadIdx.x, lane = t & 63, wid = t >> 6;
  int blk = blockIdx.x;
  *(float4*)&hl[t * 4] = *(const float4*)&h[(size_t)blk * 1024 + t * 4];
  float wreg[64];
#pragma unroll
  for (int k = 0; k < 64; ++k) wreg[k] = W[k * 64 + lane];
  float as = a[lane], ad = a[64 + lane];
  __syncthreads();
#pragma unroll
  for (int rr = 0; rr < 4; ++rr) {
    int rl = wid * 4 + rr;
    int row = blk * 16 + rl;
    float acc = 0.f;
#pragma unroll
    for (int kk = 0; kk < 16; ++kk) {
      float4 hq = *(const float4*)&hl[rl * 64 + kk * 4];   // LDS broadcast
      acc = fmaf(hq.x, wreg[kk * 4 + 0], acc);
      acc = fmaf(hq.y, wreg[kk * 4 + 1], acc);
      acc = fmaf(hq.z, wreg[kk * 4 + 2], acc);
      acc = fmaf(hq.w, wreg[kk * 4 + 3], acc);
    }
    Wh[(size_t)row * 64 + lane] = acc;
    float ps = acc * as, pd = acc * ad;
#pragma unroll
    for (int off = 32; off > 0; off >>= 1) {
      ps += __shfl_xor(ps, off, 64);
      pd += __shfl_xor(pd, off, 64);
    }
    if (lane == 0) { c[row] = ps; d[row] = pd; }
  }
}

// ---- K2: fused rank-sort + batch-max + threshold-count, 2 rows/wave --------
// Wave handles elements j0, j0+1 of one batch; a single pass over d[b,:]
// yields both ranks (exact permutation via (value,index) keys), both
// threshold counts, and the batch max. Counts packed (<=2048 fits 16b).
__global__ __launch_bounds__(256) void k_rank(const float* __restrict__ d,
                                              const float* __restrict__ c,
                                              float* __restrict__ E1,
                                              float* __restrict__ E2,
                                              int* __restrict__ perm,
                                              int* __restrict__ kidx,
                                              float* __restrict__ M) {
  int t = threadIdx.x, lane = t & 63, wid = t >> 6;
  int row0 = blockIdx.x * 8 + wid * 2;       // even; row1 = row0+1 same batch
  int b = row0 >> 11, j0 = row0 & (N - 1), j1 = j0 + 1;
  const float* db = d + b * N;
  float dj0 = db[j0], dj1 = db[j1];          // wave-uniform
  float thr0 = -c[row0], thr1 = -c[row0 + 1];
  unsigned long long k0 = ((unsigned long long)ord32(dj0) << 11) | (unsigned)j0;
  unsigned long long k1 = ((unsigned long long)ord32(dj1) << 11) | (unsigned)j1;
  int cnt0 = 0, cnt1 = 0, c20 = 0, c21 = 0;
  float m = -INFINITY;
#pragma unroll 8
  for (int it = 0; it < N / 64; ++it) {
    int jj = it * 64 + lane;
    float v = db[jj];
    unsigned long long kv = ((unsigned long long)ord32(v) << 11) | (unsigned)jj;
    cnt0 += (kv < k0) ? 1 : 0;
    cnt1 += (kv < k1) ? 1 : 0;
    c20  += (v <= thr0) ? 1 : 0;
    c21  += (v <= thr1) ? 1 : 0;
    m = fmaxf(m, v);
  }
  int pc  = cnt0 | (cnt1 << 16);
  int pc2 = c20  | (c21  << 16);
#pragma unroll
  for (int off = 32; off > 0; off >>= 1) {
    pc  += __shfl_xor(pc,  off, 64);
    pc2 += __shfl_xor(pc2, off, 64);
    m = fmaxf(m, __shfl_xor(m, off, 64));
  }
  if (lane == 0) {
    int r0 = b * N + (pc & 0xffff);
    int r1 = b * N + (pc >> 16);
    E1[r0] = __expf(dj0 - m);                // <= 1
    E2[r0] = __expf(0.2f * (dj0 - m));       // <= 1
    E1[r1] = __expf(dj1 - m);
    E2[r1] = __expf(0.2f * (dj1 - m));
    perm[r0] = j0;
    perm[r1] = j1;
    kidx[row0]     = pc2 & 0xffff;
    kidx[row0 + 1] = pc2 >> 16;
    if (j0 == 0) M[b] = m;
  }
}

// ---- K3: scans over sorted ranks -------------------------------------------
// Block per (channel o, batch b). Thread t owns ranks [8t, 8t+8). Shfl-based
// wave scans + one barrier for cross-wave bases. Output layout [b][o][k]
// (stride NKP) -> fully-coalesced float4 stores.
__global__ __launch_bounds__(256) void k_scan(const float* __restrict__ Wh,
                                              const int* __restrict__ perm,
                                              const float* __restrict__ E1,
                                              const float* __restrict__ E2,
                                              float* __restrict__ Suf,
                                              float* __restrict__ Pre) {
  __shared__ float wt1[4], wt2[4];
  int o = blockIdx.x, b = blockIdx.y;
  int t = threadIdx.x, lane = t & 63, wid = t >> 6;
  int r0 = t * 8;
  const float* Whb = Wh + (size_t)b * N * 64;
  const int* pb = perm + b * N;
  const float* e1 = E1 + b * N;
  const float* e2 = E2 + b * N;
  float x1[8], x2[8];
#pragma unroll
  for (int q = 0; q < 8; ++q) {
    int r = r0 + q;
    float val = 1.0f;
    if (o < 64) val = Whb[(size_t)pb[r] * 64 + o];
    x1[q] = e1[r] * val;
    x2[q] = e2[r] * val;
  }
  float lp[8], ss[8];
  float s2 = 0.f;
#pragma unroll
  for (int q = 0; q < 8; ++q) { s2 += x2[q]; lp[q] = s2; }
  float s1 = 0.f;
#pragma unroll
  for (int q = 7; q >= 0; --q) { s1 += x1[q]; ss[q] = s1; }
  // wave-level inclusive prefix (i2) and inclusive suffix (r1)
  float i2 = s2;
#pragma unroll
  for (int off = 1; off < 64; off <<= 1) {
    float v = __shfl_up(i2, off, 64);
    if (lane >= off) i2 += v;
  }
  float r1 = s1;
#pragma unroll
  for (int off = 1; off < 64; off <<= 1) {
    float v = __shfl_down(r1, off, 64);
    if (lane < 64 - off) r1 += v;
  }
  if (lane == 63) wt2[wid] = i2;             // wave totals
  if (lane == 0)  wt1[wid] = r1;
  __syncthreads();
  float base2 = 0.f, after1 = 0.f, tot2 = 0.f;
#pragma unroll
  for (int w = 0; w < 4; ++w) {
    float a2 = wt2[w], a1 = wt1[w];
    tot2 += a2;
    if (w < wid) base2 += a2;
    if (w > wid) after1 += a1;
  }
  float excl = base2 + (i2 - s2);            // exclusive prefix before r0
  float aftr = after1 + (r1 - s1);           // suffix strictly after r0+7
  float* Sb = Suf + ((size_t)b * ST + o) * NKP;
  float* Pb = Pre + ((size_t)b * ST + o) * NKP;
  float4 sv0 = { aftr + ss[0], aftr + ss[1], aftr + ss[2], aftr + ss[3] };
  float4 sv1 = { aftr + ss[4], aftr + ss[5], aftr + ss[6], aftr + ss[7] };
  float4 pv0 = { excl, excl + lp[0], excl + lp[1], excl + lp[2] };
  float4 pv1 = { excl + lp[3], excl + lp[4], excl + lp[5], excl + lp[6] };
  *(float4*)&Sb[r0]     = sv0;
  *(float4*)&Sb[r0 + 4] = sv1;
  *(float4*)&Pb[r0]     = pv0;
  *(float4*)&Pb[r0 + 4] = pv1;
  if (t == 255) { Sb[N] = 0.f; Pb[N] = tot2; }   // k = N boundary
}

// ---- K4: combine + ELU ------------------------------------------------------
__global__ __launch_bounds__(256) void k_final(const float* __restrict__ c,
                                               const float* __restrict__ M,
                                               const int* __restrict__ kidx,
                                               const float* __restrict__ Suf,
                                               const float* __restrict__ Pre,
                                               float* __restrict__ out) {
  int t = threadIdx.x, lane = t & 63, wid = t >> 6;
  int row = blockIdx.x * 4 + wid;
  int b = row >> 11;
  int k = kidx[row];
  float cpM = c[row] + M[b];
  float f1, f2;                              // exponents <= 0: no overflow
  if (cpM > 0.f) { f1 = 1.f;                 f2 = __expf(-0.8f * cpM); }
  else           { f1 = __expf(0.8f * cpM);  f2 = 1.f; }
  size_t basev = ((size_t)b * ST + lane) * NKP + k;   // L2-resident strided
  size_t based = ((size_t)b * ST + 64)   * NKP + k;
  float S  = Suf[basev], P  = Pre[basev];
  float Sd = Suf[based], Pd = Pre[based];
  float v = (f1 * S + f2 * P) / (f1 * Sd + f2 * Pd);
  out[(size_t)row * 64 + lane] = (v > 0.f) ? v : expm1f(v);   // ELU alpha=1
}

// ---- launch -----------------------------------------------------------------
extern "C" void kernel_launch(void* const* d_in, const int* in_sizes, int n_in,
                              void* d_out, int out_size, void* d_ws, size_t ws_size,
                              hipStream_t stream) {
  (void)in_sizes; (void)n_in; (void)out_size; (void)ws_size;
  const float* h = (const float*)d_in[0];
  const float* W = (const float*)d_in[1];
  const float* a = (const float*)d_in[2];
  float* out = (float*)d_out;

  float* ws = (float*)d_ws;
  size_t off = 0;
  float* Wh   = ws + off; off += (size_t)NROW * F;        // 4 MB
  float* c    = ws + off; off += NROW;
  float* d    = ws + off; off += NROW;
  float* E1   = ws + off; off += NROW;
  float* E2   = ws + off; off += NROW;
  float* M    = ws + off; off += 16;
  int*   perm = (int*)(ws + off); off += NROW;
  int*   kidx = (int*)(ws + off); off += NROW;
  float* Suf  = ws + off; off += (size_t)B * ST * NKP;    // 4.07 MB
  float* Pre  = ws + off; off += (size_t)B * ST * NKP;    // 4.07 MB

  k_wh   <<<NROW / 16, 256, 0, stream>>>(h, W, a, Wh, c, d);
  k_rank <<<NROW / 8,  256, 0, stream>>>(d, c, E1, E2, perm, kidx, M);
  k_scan <<<dim3(ST, B), 256, 0, stream>>>(Wh, perm, E1, E2, Suf, Pre);
  k_final<<<NROW / 4,  256, 0, stream>>>(c, M, kidx, Suf, Pre, out);
}